// Round 4
// baseline (1206.343 us; speedup 1.0000x reference)
//
#include <hip/hip_runtime.h>
#include <math.h>

#define SPAT 1600
#define BSZ 8
#define DM 256
#define NH 8
#define DH 32

// ---------------- K1: logits[b][s] = k[s][b][:] . Wp + bp ----------------
__global__ __launch_bounds__(256) void logits_kernel(
    const float* __restrict__ k, const float* __restrict__ Wp,
    const float* __restrict__ bp, float* __restrict__ logits)
{
  int wave = threadIdx.x >> 6, lane = threadIdx.x & 63;
  int idx = blockIdx.x * 4 + wave;           // 0..12799
  if (idx >= BSZ * SPAT) return;
  int b = idx / SPAT, s = idx - b * SPAT;
  const float4 kv = *(const float4*)(k + (s * BSZ + b) * DM + lane * 4);
  const float4 wv = *(const float4*)(Wp + lane * 4);
  float sum = kv.x * wv.x + kv.y * wv.y + kv.z * wv.z + kv.w * wv.w;
  #pragma unroll
  for (int off = 32; off; off >>= 1) sum += __shfl_xor(sum, off);
  if (lane == 0) logits[idx] = sum + bp[0];
}

// -------- K2: per-batch softmax -> entropy -> gaussian conv (same) --------
__global__ __launch_bounds__(256) void entropy_kernel(
    const float* __restrict__ logits, const float* __restrict__ gk,
    float* __restrict__ smooth)
{
  int b = blockIdx.x;
  int t = threadIdx.x;
  const float* L = logits + b * SPAT;
  __shared__ float entpad[SPAT + 28];
  __shared__ float red[256];

  for (int i = t; i < SPAT + 28; i += 256) entpad[i] = 0.f;

  float m = -INFINITY;
  for (int i = t; i < SPAT; i += 256) m = fmaxf(m, L[i]);
  red[t] = m; __syncthreads();
  for (int o = 128; o; o >>= 1) { if (t < o) red[t] = fmaxf(red[t], red[t + o]); __syncthreads(); }
  m = red[0]; __syncthreads();

  float lsum = 0.f;
  for (int i = t; i < SPAT; i += 256) {
    float e = expf(L[i] - m);
    entpad[14 + i] = e;
    lsum += e;
  }
  red[t] = lsum; __syncthreads();
  for (int o = 128; o; o >>= 1) { if (t < o) red[t] += red[t + o]; __syncthreads(); }
  float S = red[0]; __syncthreads();

  for (int i = t; i < SPAT; i += 256) {
    float p = entpad[14 + i] / S + 1e-8f;
    entpad[14 + i] = -p * logf(p) / 0.6931471805599453f;
  }
  __syncthreads();

  for (int i = t; i < SPAT; i += 256) {
    float acc = 0.f;
    #pragma unroll
    for (int u = 0; u < 29; ++u) acc += entpad[i + u] * gk[28 - u];
    smooth[b * SPAT + i] = acc;
  }
}

// -------- K3: sobel sign transitions -> cluster size -> meta --------
// meta: [0]=C, [1]=lo, [2]=rem, [3]=n_cl
__global__ __launch_bounds__(256) void clsize_kernel(
    const float* __restrict__ smooth, const float* __restrict__ sobel,
    int* __restrict__ meta)
{
  __shared__ int cnt;
  __shared__ float msum;
  int t = threadIdx.x;
  float sb0 = sobel[0], sb1 = sobel[1], sb2 = sobel[2];
  if (t == 0) msum = 0.f;
  for (int b = 0; b < BSZ; ++b) {
    const float* sm = smooth + b * SPAT;
    if (t == 0) cnt = 0;
    __syncthreads();
    int local = 0;
    for (int i = 1 + t; i < SPAT; i += 256) {
      float smL = (i - 2 >= 0) ? sm[i - 2] : 0.f;
      float a = sm[i - 1];
      float c = sm[i];
      float smR = (i + 1 < SPAT) ? sm[i + 1] : 0.f;
      float stepPrev = smL * sb2 + a * sb1 + c * sb0;   // step[i-1]
      float stepCur  = a * sb2 + c * sb1 + smR * sb0;   // step[i]
      int sPrev = stepPrev > 0.f;
      int sCur  = stepCur  > 0.f;
      local += (sPrev != sCur);
    }
    atomicAdd(&cnt, local);
    __syncthreads();
    if (t == 0) msum += 1600.f / (float)(cnt + 1);
    __syncthreads();
  }
  if (t == 0) {
    float mean = msum / 8.f;
    int C = (int)rintf(mean);
    if (C < 1) C = 1;
    int rem = SPAT % C;
    int lo = rem / 2;
    int n_cl = (SPAT - rem) / C;
    meta[0] = C; meta[1] = lo; meta[2] = rem; meta[3] = n_cl;
  }
}

// -------- K4: entropy-softmax weighted cluster pooling of k, v --------
__global__ __launch_bounds__(256) void cluster_kernel(
    const float* __restrict__ k, const float* __restrict__ v,
    const float* __restrict__ smooth, const int* __restrict__ meta,
    float* __restrict__ kc, float* __restrict__ vc)
{
  int c = blockIdx.x, b = blockIdx.y;
  int C = meta[0], lo = meta[1], n_cl = meta[3];
  if (c >= n_cl) return;
  __shared__ float w[SPAT];
  __shared__ float red[256];
  int t = threadIdx.x;
  const float* sm = smooth + b * SPAT + lo + c * C;

  float m = -INFINITY;
  for (int j = t; j < C; j += 256) m = fmaxf(m, sm[j]);
  red[t] = m; __syncthreads();
  for (int o = 128; o; o >>= 1) { if (t < o) red[t] = fmaxf(red[t], red[t + o]); __syncthreads(); }
  m = red[0]; __syncthreads();

  float lsum = 0.f;
  for (int j = t; j < C; j += 256) { float e = expf(sm[j] - m); w[j] = e; lsum += e; }
  red[t] = lsum; __syncthreads();
  for (int o = 128; o; o >>= 1) { if (t < o) red[t] += red[t + o]; __syncthreads(); }
  float S = red[0]; __syncthreads();
  for (int j = t; j < C; j += 256) w[j] = w[j] / S;
  __syncthreads();

  int d = t;
  int s0 = lo + c * C;
  const float* kp = k + (s0 * BSZ + b) * DM + d;
  const float* vp = v + (s0 * BSZ + b) * DM + d;
  float ak = 0.f, av = 0.f;
  for (int j = 0; j < C; ++j) {
    float wj = w[j];
    ak += wj * kp[0];
    av += wj * vp[0];
    kp += BSZ * DM; vp += BSZ * DM;
  }
  kc[(b * SPAT + c) * DM + d] = ak;
  vc[(b * SPAT + c) * DM + d] = av;
}

// -------- K5/K7: tiled fp32 GEMM: C[r][n] = A[r][:] @ W + bias --------
// mode 0: A gathered from q layout (s,b,d); out linear [b*1600+s]
// mode 1: A linear, rows with (r%1600)>=n_cl invalid (skipped)
// mode 2: A linear; out remapped to (s*8+b)*256 (final output transpose)
__global__ __launch_bounds__(256) void gemm_kernel(
    const float* __restrict__ A, const float* __restrict__ W,
    const float* __restrict__ bias, float* __restrict__ Cout,
    int mode, const int* __restrict__ meta)
{
  __shared__ float As[16][68];
  __shared__ float Ws[16][68];
  int bm = blockIdx.x, bn = blockIdx.y;
  int row0 = bm * 64, col0 = bn * 64;
  int n_cl = SPAT;
  if (mode == 1) {
    n_cl = meta[3];
    int s0 = row0 % SPAT;            // 1600/64==25 -> block stays within one b
    if (s0 >= n_cl) return;
  }
  int tid = threadIdx.x;
  int mA = tid >> 2, kA = (tid & 3) * 4;
  int kW = tid >> 4, nW = (tid & 15) * 4;
  int r = row0 + mA;
  const float* Arow;
  if (mode == 0) { int b = r / SPAT, s = r - b * SPAT; Arow = A + (s * BSZ + b) * DM; }
  else           { Arow = A + r * DM; }
  const float* Wrow = W + kW * DM + col0 + nW;
  int ty = tid >> 4, tx = tid & 15;
  float acc[4][4] = {};

  for (int k0 = 0; k0 < DM; k0 += 16) {
    float4 a4 = *(const float4*)(Arow + k0 + kA);
    As[kA + 0][mA] = a4.x; As[kA + 1][mA] = a4.y;
    As[kA + 2][mA] = a4.z; As[kA + 3][mA] = a4.w;
    float4 w4 = *(const float4*)(Wrow + k0 * DM);
    *(float4*)&Ws[kW][nW] = w4;
    __syncthreads();
    #pragma unroll
    for (int kk = 0; kk < 16; ++kk) {
      float4 av = *(const float4*)&As[kk][ty * 4];
      float4 wv = *(const float4*)&Ws[kk][tx * 4];
      acc[0][0] += av.x * wv.x; acc[0][1] += av.x * wv.y; acc[0][2] += av.x * wv.z; acc[0][3] += av.x * wv.w;
      acc[1][0] += av.y * wv.x; acc[1][1] += av.y * wv.y; acc[1][2] += av.y * wv.z; acc[1][3] += av.y * wv.w;
      acc[2][0] += av.z * wv.x; acc[2][1] += av.z * wv.y; acc[2][2] += av.z * wv.z; acc[2][3] += av.z * wv.w;
      acc[3][0] += av.w * wv.x; acc[3][1] += av.w * wv.y; acc[3][2] += av.w * wv.z; acc[3][3] += av.w * wv.w;
    }
    __syncthreads();
  }

  float4 bi = *(const float4*)(bias + col0 + tx * 4);
  #pragma unroll
  for (int i = 0; i < 4; ++i) {
    int rr = row0 + ty * 4 + i;
    int bb = rr / SPAT, ss = rr - bb * SPAT;
    if (mode == 1 && ss >= n_cl) continue;
    float* outp;
    if (mode == 2) outp = Cout + (ss * BSZ + bb) * DM + col0 + tx * 4;
    else           outp = Cout + rr * DM + col0 + tx * 4;
    float4 o;
    o.x = acc[i][0] + bi.x; o.y = acc[i][1] + bi.y;
    o.z = acc[i][2] + bi.z; o.w = acc[i][3] + bi.w;
    *(float4*)outp = o;
  }
}

// -------- K6: attention, 4-way cluster-split per q-row --------
// lane = (q-row, sub); sub in 0..3 owns clusters [c0+8*sub, c0+8*sub+8).
// 6400 waves total; partial (m,l,acc) merged via 4-lane shfl butterfly.
#define CHL 8
__global__ __launch_bounds__(256, 4) void attn_kernel(
    const float* __restrict__ Qp, const float* __restrict__ Kp,
    const float* __restrict__ Vp, const int* __restrict__ meta,
    float* __restrict__ ctx)
{
  int b = blockIdx.y, h = blockIdx.z;
  int t = threadIdx.x;
  int sub = t & 3;
  int s = blockIdx.x * 64 + (t >> 2);         // 25*64 == 1600
  int n_cl = meta[3];

  const float* qrow = Qp + (b * SPAT + s) * DM + h * DH;
  float4 q[8];
  #pragma unroll
  for (int i = 0; i < 8; ++i) q[i] = *(const float4*)(qrow + i * 4);

  float4 acc[8];
  #pragma unroll
  for (int i = 0; i < 8; ++i) acc[i] = make_float4(0.f, 0.f, 0.f, 0.f);
  float m = -1e30f, l = 0.f;                  // finite init: no inf-inf NaN

  const float* Kb = Kp + (b * SPAT) * DM + h * DH;
  const float* Vb = Vp + (b * SPAT) * DM + h * DH;

  for (int c0 = 0; c0 < n_cl; c0 += 4 * CHL) {
    int cbase = c0 + sub * CHL;               // max row 1599, always in-buffer
    float sc[CHL];
    #pragma unroll
    for (int j = 0; j < CHL; ++j) {
      const float* kr = Kb + (cbase + j) * DM;
      float d0 = 0.f, d1 = 0.f, d2 = 0.f, d3 = 0.f;
      #pragma unroll
      for (int i = 0; i < 8; ++i) {
        float4 kv = *(const float4*)(kr + i * 4);
        d0 = fmaf(q[i].x, kv.x, d0);
        d1 = fmaf(q[i].y, kv.y, d1);
        d2 = fmaf(q[i].z, kv.z, d2);
        d3 = fmaf(q[i].w, kv.w, d3);
      }
      sc[j] = (d0 + d1) + (d2 + d3);
    }
    #pragma unroll
    for (int j = 0; j < CHL; ++j) sc[j] = (cbase + j < n_cl) ? sc[j] : -INFINITY;

    float mc = sc[0];
    #pragma unroll
    for (int j = 1; j < CHL; ++j) mc = fmaxf(mc, sc[j]);
    float nm = fmaxf(m, mc);                  // finite (>= -1e30)
    float corr = __expf(m - nm);
    m = nm;
    l *= corr;
    #pragma unroll
    for (int i = 0; i < 8; ++i) {
      acc[i].x *= corr; acc[i].y *= corr; acc[i].z *= corr; acc[i].w *= corr;
    }
    #pragma unroll
    for (int j = 0; j < CHL; ++j) {
      float p = __expf(sc[j] - m);            // exp(-inf)=0 for masked tail
      l += p;
      const float* vr = Vb + (cbase + j) * DM;
      #pragma unroll
      for (int i = 0; i < 8; ++i) {
        float4 vv = *(const float4*)(vr + i * 4);
        acc[i].x = fmaf(p, vv.x, acc[i].x);
        acc[i].y = fmaf(p, vv.y, acc[i].y);
        acc[i].z = fmaf(p, vv.z, acc[i].z);
        acc[i].w = fmaf(p, vv.w, acc[i].w);
      }
    }
  }

  // merge 4 partials within the 4-lane group
  float M = m;
  M = fmaxf(M, __shfl_xor(M, 1));
  M = fmaxf(M, __shfl_xor(M, 2));
  float f = __expf(m - M);                    // empty stripe: exp(-1e30-M)=0
  l *= f;
  l += __shfl_xor(l, 1);
  l += __shfl_xor(l, 2);
  #pragma unroll
  for (int i = 0; i < 8; ++i) {
    acc[i].x *= f; acc[i].y *= f; acc[i].z *= f; acc[i].w *= f;
    acc[i].x += __shfl_xor(acc[i].x, 1); acc[i].x += __shfl_xor(acc[i].x, 2);
    acc[i].y += __shfl_xor(acc[i].y, 1); acc[i].y += __shfl_xor(acc[i].y, 2);
    acc[i].z += __shfl_xor(acc[i].z, 1); acc[i].z += __shfl_xor(acc[i].z, 2);
    acc[i].w += __shfl_xor(acc[i].w, 1); acc[i].w += __shfl_xor(acc[i].w, 2);
  }

  float inv = 1.f / (l * 32.f);
  float* orow = ctx + (b * SPAT + s) * DM + h * DH + sub * 8;
  float4 o0 = acc[sub * 2], o1 = acc[sub * 2 + 1];
  o0.x *= inv; o0.y *= inv; o0.z *= inv; o0.w *= inv;
  o1.x *= inv; o1.y *= inv; o1.z *= inv; o1.w *= inv;
  *(float4*)(orow) = o0;
  *(float4*)(orow + 4) = o1;
}

extern "C" void kernel_launch(void* const* d_in, const int* in_sizes, int n_in,
                              void* d_out, int out_size, void* d_ws, size_t ws_size,
                              hipStream_t stream) {
  const float* q  = (const float*)d_in[0];
  const float* k  = (const float*)d_in[1];
  const float* v  = (const float*)d_in[2];
  const float* Wq = (const float*)d_in[5];
  const float* bq = (const float*)d_in[6];
  const float* Wk = (const float*)d_in[7];
  const float* bk = (const float*)d_in[8];
  const float* Wv = (const float*)d_in[9];
  const float* bv = (const float*)d_in[10];
  const float* Wo = (const float*)d_in[11];
  const float* bo = (const float*)d_in[12];
  const float* Wp = (const float*)d_in[13];
  const float* bp = (const float*)d_in[14];
  const float* gk = (const float*)d_in[15];
  const float* sb = (const float*)d_in[16];
  float* out = (float*)d_out;

  char* ws = (char*)d_ws;
  int*   meta   = (int*)ws;                                  // 256 B
  float* logits = (float*)(ws + 256);                        // 12800 f32
  float* smooth = logits + BSZ * SPAT;                       // 12800 f32
  float* bufA   = (float*)(ws + 256 + 2 * BSZ * SPAT * 4);   // 13.1 MB: kc, then Vp
  float* bufB   = bufA + BSZ * SPAT * DM;                    // vc, then ctx
  float* bufC   = bufB + BSZ * SPAT * DM;                    // Qp
  float* bufD   = bufC + BSZ * SPAT * DM;                    // Kp

  logits_kernel<<<BSZ * SPAT / 4, 256, 0, stream>>>(k, Wp, bp, logits);
  entropy_kernel<<<BSZ, 256, 0, stream>>>(logits, gk, smooth);
  clsize_kernel<<<1, 256, 0, stream>>>(smooth, sb, meta);
  cluster_kernel<<<dim3(SPAT, BSZ), 256, 0, stream>>>(k, v, smooth, meta, bufA, bufB);
  gemm_kernel<<<dim3(200, 4), 256, 0, stream>>>(q,    Wq, bq, bufC, 0, meta);  // Qp
  gemm_kernel<<<dim3(200, 4), 256, 0, stream>>>(bufA, Wk, bk, bufD, 1, meta);  // Kp
  gemm_kernel<<<dim3(200, 4), 256, 0, stream>>>(bufB, Wv, bv, bufA, 1, meta);  // Vp (reuse kc)
  attn_kernel<<<dim3(25, BSZ, NH), 256, 0, stream>>>(bufC, bufD, bufA, meta, bufB); // ctx (reuse vc)
  gemm_kernel<<<dim3(200, 4), 256, 0, stream>>>(bufB, Wo, bo, out, 2, meta);   // final + transpose
}

// Round 5
// 1048.594 us; speedup vs baseline: 1.1504x; 1.1504x over previous
//
#include <hip/hip_runtime.h>
#include <math.h>

#define SPAT 1600
#define BSZ 8
#define DM 256
#define NH 8
#define DH 32

// ---------------- K1: logits[b][s] = k[s][b][:] . Wp + bp ----------------
__global__ __launch_bounds__(256) void logits_kernel(
    const float* __restrict__ k, const float* __restrict__ Wp,
    const float* __restrict__ bp, float* __restrict__ logits)
{
  int wave = threadIdx.x >> 6, lane = threadIdx.x & 63;
  int idx = blockIdx.x * 4 + wave;           // 0..12799
  if (idx >= BSZ * SPAT) return;
  int b = idx / SPAT, s = idx - b * SPAT;
  const float4 kv = *(const float4*)(k + (s * BSZ + b) * DM + lane * 4);
  const float4 wv = *(const float4*)(Wp + lane * 4);
  float sum = kv.x * wv.x + kv.y * wv.y + kv.z * wv.z + kv.w * wv.w;
  #pragma unroll
  for (int off = 32; off; off >>= 1) sum += __shfl_xor(sum, off);
  if (lane == 0) logits[idx] = sum + bp[0];
}

// -------- K2: per-batch softmax -> entropy -> gaussian conv (same) --------
__global__ __launch_bounds__(256) void entropy_kernel(
    const float* __restrict__ logits, const float* __restrict__ gk,
    float* __restrict__ smooth)
{
  int b = blockIdx.x;
  int t = threadIdx.x;
  const float* L = logits + b * SPAT;
  __shared__ float entpad[SPAT + 28];
  __shared__ float red[256];

  for (int i = t; i < SPAT + 28; i += 256) entpad[i] = 0.f;

  float m = -INFINITY;
  for (int i = t; i < SPAT; i += 256) m = fmaxf(m, L[i]);
  red[t] = m; __syncthreads();
  for (int o = 128; o; o >>= 1) { if (t < o) red[t] = fmaxf(red[t], red[t + o]); __syncthreads(); }
  m = red[0]; __syncthreads();

  float lsum = 0.f;
  for (int i = t; i < SPAT; i += 256) {
    float e = expf(L[i] - m);
    entpad[14 + i] = e;
    lsum += e;
  }
  red[t] = lsum; __syncthreads();
  for (int o = 128; o; o >>= 1) { if (t < o) red[t] += red[t + o]; __syncthreads(); }
  float S = red[0]; __syncthreads();

  for (int i = t; i < SPAT; i += 256) {
    float p = entpad[14 + i] / S + 1e-8f;
    entpad[14 + i] = -p * logf(p) / 0.6931471805599453f;
  }
  __syncthreads();

  for (int i = t; i < SPAT; i += 256) {
    float acc = 0.f;
    #pragma unroll
    for (int u = 0; u < 29; ++u) acc += entpad[i + u] * gk[28 - u];
    smooth[b * SPAT + i] = acc;
  }
}

// -------- K3: sobel sign transitions -> cluster size -> meta --------
// meta: [0]=C, [1]=lo, [2]=rem, [3]=n_cl
__global__ __launch_bounds__(256) void clsize_kernel(
    const float* __restrict__ smooth, const float* __restrict__ sobel,
    int* __restrict__ meta)
{
  __shared__ int cnt;
  __shared__ float msum;
  int t = threadIdx.x;
  float sb0 = sobel[0], sb1 = sobel[1], sb2 = sobel[2];
  if (t == 0) msum = 0.f;
  for (int b = 0; b < BSZ; ++b) {
    const float* sm = smooth + b * SPAT;
    if (t == 0) cnt = 0;
    __syncthreads();
    int local = 0;
    for (int i = 1 + t; i < SPAT; i += 256) {
      float smL = (i - 2 >= 0) ? sm[i - 2] : 0.f;
      float a = sm[i - 1];
      float c = sm[i];
      float smR = (i + 1 < SPAT) ? sm[i + 1] : 0.f;
      float stepPrev = smL * sb2 + a * sb1 + c * sb0;   // step[i-1]
      float stepCur  = a * sb2 + c * sb1 + smR * sb0;   // step[i]
      int sPrev = stepPrev > 0.f;
      int sCur  = stepCur  > 0.f;
      local += (sPrev != sCur);
    }
    atomicAdd(&cnt, local);
    __syncthreads();
    if (t == 0) msum += 1600.f / (float)(cnt + 1);
    __syncthreads();
  }
  if (t == 0) {
    float mean = msum / 8.f;
    int C = (int)rintf(mean);
    if (C < 1) C = 1;
    int rem = SPAT % C;
    int lo = rem / 2;
    int n_cl = (SPAT - rem) / C;
    meta[0] = C; meta[1] = lo; meta[2] = rem; meta[3] = n_cl;
  }
}

// -------- K4: entropy-softmax weighted cluster pooling of k, v --------
__global__ __launch_bounds__(256) void cluster_kernel(
    const float* __restrict__ k, const float* __restrict__ v,
    const float* __restrict__ smooth, const int* __restrict__ meta,
    float* __restrict__ kc, float* __restrict__ vc)
{
  int c = blockIdx.x, b = blockIdx.y;
  int C = meta[0], lo = meta[1], n_cl = meta[3];
  if (c >= n_cl) return;
  __shared__ float w[SPAT];
  __shared__ float red[256];
  int t = threadIdx.x;
  const float* sm = smooth + b * SPAT + lo + c * C;

  float m = -INFINITY;
  for (int j = t; j < C; j += 256) m = fmaxf(m, sm[j]);
  red[t] = m; __syncthreads();
  for (int o = 128; o; o >>= 1) { if (t < o) red[t] = fmaxf(red[t], red[t + o]); __syncthreads(); }
  m = red[0]; __syncthreads();

  float lsum = 0.f;
  for (int j = t; j < C; j += 256) { float e = expf(sm[j] - m); w[j] = e; lsum += e; }
  red[t] = lsum; __syncthreads();
  for (int o = 128; o; o >>= 1) { if (t < o) red[t] += red[t + o]; __syncthreads(); }
  float S = red[0]; __syncthreads();
  for (int j = t; j < C; j += 256) w[j] = w[j] / S;
  __syncthreads();

  int d = t;
  int s0 = lo + c * C;
  const float* kp = k + (s0 * BSZ + b) * DM + d;
  const float* vp = v + (s0 * BSZ + b) * DM + d;
  float ak = 0.f, av = 0.f;
  for (int j = 0; j < C; ++j) {
    float wj = w[j];
    ak += wj * kp[0];
    av += wj * vp[0];
    kp += BSZ * DM; vp += BSZ * DM;
  }
  kc[(b * SPAT + c) * DM + d] = ak;
  vc[(b * SPAT + c) * DM + d] = av;
}

// -------- K5/K7: tiled fp32 GEMM: C[r][n] = A[r][:] @ W + bias --------
// mode 0: A gathered from q layout (s,b,d); out linear [b*1600+s]
// mode 1: A linear, rows with (r%1600)>=n_cl invalid (skipped)
// mode 2: A linear; out remapped to (s*8+b)*256 (final output transpose)
__global__ __launch_bounds__(256) void gemm_kernel(
    const float* __restrict__ A, const float* __restrict__ W,
    const float* __restrict__ bias, float* __restrict__ Cout,
    int mode, const int* __restrict__ meta)
{
  __shared__ float As[16][68];
  __shared__ float Ws[16][68];
  int bm = blockIdx.x, bn = blockIdx.y;
  int row0 = bm * 64, col0 = bn * 64;
  int n_cl = SPAT;
  if (mode == 1) {
    n_cl = meta[3];
    int s0 = row0 % SPAT;            // 1600/64==25 -> block stays within one b
    if (s0 >= n_cl) return;
  }
  int tid = threadIdx.x;
  int mA = tid >> 2, kA = (tid & 3) * 4;
  int kW = tid >> 4, nW = (tid & 15) * 4;
  int r = row0 + mA;
  const float* Arow;
  if (mode == 0) { int b = r / SPAT, s = r - b * SPAT; Arow = A + (s * BSZ + b) * DM; }
  else           { Arow = A + r * DM; }
  const float* Wrow = W + kW * DM + col0 + nW;
  int ty = tid >> 4, tx = tid & 15;
  float acc[4][4] = {};

  for (int k0 = 0; k0 < DM; k0 += 16) {
    float4 a4 = *(const float4*)(Arow + k0 + kA);
    As[kA + 0][mA] = a4.x; As[kA + 1][mA] = a4.y;
    As[kA + 2][mA] = a4.z; As[kA + 3][mA] = a4.w;
    float4 w4 = *(const float4*)(Wrow + k0 * DM);
    *(float4*)&Ws[kW][nW] = w4;
    __syncthreads();
    #pragma unroll
    for (int kk = 0; kk < 16; ++kk) {
      float4 av = *(const float4*)&As[kk][ty * 4];
      float4 wv = *(const float4*)&Ws[kk][tx * 4];
      acc[0][0] += av.x * wv.x; acc[0][1] += av.x * wv.y; acc[0][2] += av.x * wv.z; acc[0][3] += av.x * wv.w;
      acc[1][0] += av.y * wv.x; acc[1][1] += av.y * wv.y; acc[1][2] += av.y * wv.z; acc[1][3] += av.y * wv.w;
      acc[2][0] += av.z * wv.x; acc[2][1] += av.z * wv.y; acc[2][2] += av.z * wv.z; acc[2][3] += av.z * wv.w;
      acc[3][0] += av.w * wv.x; acc[3][1] += av.w * wv.y; acc[3][2] += av.w * wv.z; acc[3][3] += av.w * wv.w;
    }
    __syncthreads();
  }

  float4 bi = *(const float4*)(bias + col0 + tx * 4);
  #pragma unroll
  for (int i = 0; i < 4; ++i) {
    int rr = row0 + ty * 4 + i;
    int bb = rr / SPAT, ss = rr - bb * SPAT;
    if (mode == 1 && ss >= n_cl) continue;
    float* outp;
    if (mode == 2) outp = Cout + (ss * BSZ + bb) * DM + col0 + tx * 4;
    else           outp = Cout + rr * DM + col0 + tx * 4;
    float4 o;
    o.x = acc[i][0] + bi.x; o.y = acc[i][1] + bi.y;
    o.z = acc[i][2] + bi.z; o.w = acc[i][3] + bi.w;
    *(float4*)outp = o;
  }
}

// -------- K6: attention, 4-way cluster-split per q-row --------
// lane = (q-row, sub); sub in 0..3 owns clusters [c0+8*sub, c0+8*sub+8).
// 6400 waves total; partial (m,l,acc) merged via 4-lane shfl butterfly.
// NOTE: no min-waves hint — needs ~100 VGPR; forcing 64 spilled ~1 GB to
// scratch (round-4: FETCH 489 MB, WRITE 507 MB, VALUBusy 5%).
#define CHL 8
__global__ __launch_bounds__(256) void attn_kernel(
    const float* __restrict__ Qp, const float* __restrict__ Kp,
    const float* __restrict__ Vp, const int* __restrict__ meta,
    float* __restrict__ ctx)
{
  int b = blockIdx.y, h = blockIdx.z;
  int t = threadIdx.x;
  int sub = t & 3;
  int s = blockIdx.x * 64 + (t >> 2);         // 25*64 == 1600
  int n_cl = meta[3];

  const float* qrow = Qp + (b * SPAT + s) * DM + h * DH;
  float4 q[8];
  #pragma unroll
  for (int i = 0; i < 8; ++i) q[i] = *(const float4*)(qrow + i * 4);

  float4 acc[8];
  #pragma unroll
  for (int i = 0; i < 8; ++i) acc[i] = make_float4(0.f, 0.f, 0.f, 0.f);
  float m = -1e30f, l = 0.f;                  // finite init: no inf-inf NaN

  const float* Kb = Kp + (b * SPAT) * DM + h * DH;
  const float* Vb = Vp + (b * SPAT) * DM + h * DH;

  for (int c0 = 0; c0 < n_cl; c0 += 4 * CHL) {
    int cbase = c0 + sub * CHL;               // max row 1599, always in-buffer
    float sc[CHL];
    #pragma unroll
    for (int j = 0; j < CHL; ++j) {
      const float* kr = Kb + (cbase + j) * DM;
      float d0 = 0.f, d1 = 0.f, d2 = 0.f, d3 = 0.f;
      #pragma unroll
      for (int i = 0; i < 8; ++i) {
        float4 kv = *(const float4*)(kr + i * 4);
        d0 = fmaf(q[i].x, kv.x, d0);
        d1 = fmaf(q[i].y, kv.y, d1);
        d2 = fmaf(q[i].z, kv.z, d2);
        d3 = fmaf(q[i].w, kv.w, d3);
      }
      sc[j] = (d0 + d1) + (d2 + d3);
    }
    #pragma unroll
    for (int j = 0; j < CHL; ++j) sc[j] = (cbase + j < n_cl) ? sc[j] : -INFINITY;

    float mc = sc[0];
    #pragma unroll
    for (int j = 1; j < CHL; ++j) mc = fmaxf(mc, sc[j]);
    float nm = fmaxf(m, mc);                  // finite (>= -1e30)
    float corr = __expf(m - nm);
    m = nm;
    l *= corr;
    #pragma unroll
    for (int i = 0; i < 8; ++i) {
      acc[i].x *= corr; acc[i].y *= corr; acc[i].z *= corr; acc[i].w *= corr;
    }
    #pragma unroll
    for (int j = 0; j < CHL; ++j) {
      float p = __expf(sc[j] - m);            // exp(-inf)=0 for masked tail
      l += p;
      const float* vr = Vb + (cbase + j) * DM;
      #pragma unroll
      for (int i = 0; i < 8; ++i) {
        float4 vv = *(const float4*)(vr + i * 4);
        acc[i].x = fmaf(p, vv.x, acc[i].x);
        acc[i].y = fmaf(p, vv.y, acc[i].y);
        acc[i].z = fmaf(p, vv.z, acc[i].z);
        acc[i].w = fmaf(p, vv.w, acc[i].w);
      }
    }
  }

  // merge 4 partials within the 4-lane group
  float M = m;
  M = fmaxf(M, __shfl_xor(M, 1));
  M = fmaxf(M, __shfl_xor(M, 2));
  float f = __expf(m - M);                    // empty stripe: exp(-1e30-M)=0
  l *= f;
  l += __shfl_xor(l, 1);
  l += __shfl_xor(l, 2);
  #pragma unroll
  for (int i = 0; i < 8; ++i) {
    acc[i].x *= f; acc[i].y *= f; acc[i].z *= f; acc[i].w *= f;
    acc[i].x += __shfl_xor(acc[i].x, 1); acc[i].x += __shfl_xor(acc[i].x, 2);
    acc[i].y += __shfl_xor(acc[i].y, 1); acc[i].y += __shfl_xor(acc[i].y, 2);
    acc[i].z += __shfl_xor(acc[i].z, 1); acc[i].z += __shfl_xor(acc[i].z, 2);
    acc[i].w += __shfl_xor(acc[i].w, 1); acc[i].w += __shfl_xor(acc[i].w, 2);
  }

  float inv = 1.f / (l * 32.f);
  float* orow = ctx + (b * SPAT + s) * DM + h * DH + sub * 8;
  float4 o0 = acc[sub * 2], o1 = acc[sub * 2 + 1];
  o0.x *= inv; o0.y *= inv; o0.z *= inv; o0.w *= inv;
  o1.x *= inv; o1.y *= inv; o1.z *= inv; o1.w *= inv;
  *(float4*)(orow) = o0;
  *(float4*)(orow + 4) = o1;
}

extern "C" void kernel_launch(void* const* d_in, const int* in_sizes, int n_in,
                              void* d_out, int out_size, void* d_ws, size_t ws_size,
                              hipStream_t stream) {
  const float* q  = (const float*)d_in[0];
  const float* k  = (const float*)d_in[1];
  const float* v  = (const float*)d_in[2];
  const float* Wq = (const float*)d_in[5];
  const float* bq = (const float*)d_in[6];
  const float* Wk = (const float*)d_in[7];
  const float* bk = (const float*)d_in[8];
  const float* Wv = (const float*)d_in[9];
  const float* bv = (const float*)d_in[10];
  const float* Wo = (const float*)d_in[11];
  const float* bo = (const float*)d_in[12];
  const float* Wp = (const float*)d_in[13];
  const float* bp = (const float*)d_in[14];
  const float* gk = (const float*)d_in[15];
  const float* sb = (const float*)d_in[16];
  float* out = (float*)d_out;

  char* ws = (char*)d_ws;
  int*   meta   = (int*)ws;                                  // 256 B
  float* logits = (float*)(ws + 256);                        // 12800 f32
  float* smooth = logits + BSZ * SPAT;                       // 12800 f32
  float* bufA   = (float*)(ws + 256 + 2 * BSZ * SPAT * 4);   // 13.1 MB: kc, then Vp
  float* bufB   = bufA + BSZ * SPAT * DM;                    // vc, then ctx
  float* bufC   = bufB + BSZ * SPAT * DM;                    // Qp
  float* bufD   = bufC + BSZ * SPAT * DM;                    // Kp

  logits_kernel<<<BSZ * SPAT / 4, 256, 0, stream>>>(k, Wp, bp, logits);
  entropy_kernel<<<BSZ, 256, 0, stream>>>(logits, gk, smooth);
  clsize_kernel<<<1, 256, 0, stream>>>(smooth, sb, meta);
  cluster_kernel<<<dim3(SPAT, BSZ), 256, 0, stream>>>(k, v, smooth, meta, bufA, bufB);
  gemm_kernel<<<dim3(200, 4), 256, 0, stream>>>(q,    Wq, bq, bufC, 0, meta);  // Qp
  gemm_kernel<<<dim3(200, 4), 256, 0, stream>>>(bufA, Wk, bk, bufD, 1, meta);  // Kp
  gemm_kernel<<<dim3(200, 4), 256, 0, stream>>>(bufB, Wv, bv, bufA, 1, meta);  // Vp (reuse kc)
  attn_kernel<<<dim3(25, BSZ, NH), 256, 0, stream>>>(bufC, bufD, bufA, meta, bufB); // ctx (reuse vc)
  gemm_kernel<<<dim3(200, 4), 256, 0, stream>>>(bufB, Wo, bo, out, 2, meta);   // final + transpose
}

// Round 6
// 283.719 us; speedup vs baseline: 4.2519x; 3.6959x over previous
//
#include <hip/hip_runtime.h>
#include <math.h>

#define SPAT 1600
#define BSZ 8
#define DM 256
#define NH 8
#define DH 32

// ---------------- K1: logits[b][s] = k[s][b][:] . Wp + bp ----------------
__global__ __launch_bounds__(256) void logits_kernel(
    const float* __restrict__ k, const float* __restrict__ Wp,
    const float* __restrict__ bp, float* __restrict__ logits)
{
  int wave = threadIdx.x >> 6, lane = threadIdx.x & 63;
  int idx = blockIdx.x * 4 + wave;           // 0..12799
  if (idx >= BSZ * SPAT) return;
  int b = idx / SPAT, s = idx - b * SPAT;
  const float4 kv = *(const float4*)(k + (s * BSZ + b) * DM + lane * 4);
  const float4 wv = *(const float4*)(Wp + lane * 4);
  float sum = kv.x * wv.x + kv.y * wv.y + kv.z * wv.z + kv.w * wv.w;
  #pragma unroll
  for (int off = 32; off; off >>= 1) sum += __shfl_xor(sum, off);
  if (lane == 0) logits[idx] = sum + bp[0];
}

// -------- K2: per-batch softmax -> entropy -> gaussian conv (same) --------
__global__ __launch_bounds__(256) void entropy_kernel(
    const float* __restrict__ logits, const float* __restrict__ gk,
    float* __restrict__ smooth)
{
  int b = blockIdx.x;
  int t = threadIdx.x;
  const float* L = logits + b * SPAT;
  __shared__ float entpad[SPAT + 28];
  __shared__ float red[256];

  for (int i = t; i < SPAT + 28; i += 256) entpad[i] = 0.f;

  float m = -INFINITY;
  for (int i = t; i < SPAT; i += 256) m = fmaxf(m, L[i]);
  red[t] = m; __syncthreads();
  for (int o = 128; o; o >>= 1) { if (t < o) red[t] = fmaxf(red[t], red[t + o]); __syncthreads(); }
  m = red[0]; __syncthreads();

  float lsum = 0.f;
  for (int i = t; i < SPAT; i += 256) {
    float e = expf(L[i] - m);
    entpad[14 + i] = e;
    lsum += e;
  }
  red[t] = lsum; __syncthreads();
  for (int o = 128; o; o >>= 1) { if (t < o) red[t] += red[t + o]; __syncthreads(); }
  float S = red[0]; __syncthreads();

  for (int i = t; i < SPAT; i += 256) {
    float p = entpad[14 + i] / S + 1e-8f;
    entpad[14 + i] = -p * logf(p) / 0.6931471805599453f;
  }
  __syncthreads();

  for (int i = t; i < SPAT; i += 256) {
    float acc = 0.f;
    #pragma unroll
    for (int u = 0; u < 29; ++u) acc += entpad[i + u] * gk[28 - u];
    smooth[b * SPAT + i] = acc;
  }
}

// -------- K3: sobel sign transitions -> cluster size -> meta --------
// meta: [0]=C, [1]=lo, [2]=rem, [3]=n_cl
__global__ __launch_bounds__(256) void clsize_kernel(
    const float* __restrict__ smooth, const float* __restrict__ sobel,
    int* __restrict__ meta)
{
  __shared__ int cnt;
  __shared__ float msum;
  int t = threadIdx.x;
  float sb0 = sobel[0], sb1 = sobel[1], sb2 = sobel[2];
  if (t == 0) msum = 0.f;
  for (int b = 0; b < BSZ; ++b) {
    const float* sm = smooth + b * SPAT;
    if (t == 0) cnt = 0;
    __syncthreads();
    int local = 0;
    for (int i = 1 + t; i < SPAT; i += 256) {
      float smL = (i - 2 >= 0) ? sm[i - 2] : 0.f;
      float a = sm[i - 1];
      float c = sm[i];
      float smR = (i + 1 < SPAT) ? sm[i + 1] : 0.f;
      float stepPrev = smL * sb2 + a * sb1 + c * sb0;   // step[i-1]
      float stepCur  = a * sb2 + c * sb1 + smR * sb0;   // step[i]
      int sPrev = stepPrev > 0.f;
      int sCur  = stepCur  > 0.f;
      local += (sPrev != sCur);
    }
    atomicAdd(&cnt, local);
    __syncthreads();
    if (t == 0) msum += 1600.f / (float)(cnt + 1);
    __syncthreads();
  }
  if (t == 0) {
    float mean = msum / 8.f;
    int C = (int)rintf(mean);
    if (C < 1) C = 1;
    int rem = SPAT % C;
    int lo = rem / 2;
    int n_cl = (SPAT - rem) / C;
    meta[0] = C; meta[1] = lo; meta[2] = rem; meta[3] = n_cl;
  }
}

// -------- K4: entropy-softmax weighted cluster pooling of k, v --------
__global__ __launch_bounds__(256) void cluster_kernel(
    const float* __restrict__ k, const float* __restrict__ v,
    const float* __restrict__ smooth, const int* __restrict__ meta,
    float* __restrict__ kc, float* __restrict__ vc)
{
  int c = blockIdx.x, b = blockIdx.y;
  int C = meta[0], lo = meta[1], n_cl = meta[3];
  if (c >= n_cl) return;
  __shared__ float w[SPAT];
  __shared__ float red[256];
  int t = threadIdx.x;
  const float* sm = smooth + b * SPAT + lo + c * C;

  float m = -INFINITY;
  for (int j = t; j < C; j += 256) m = fmaxf(m, sm[j]);
  red[t] = m; __syncthreads();
  for (int o = 128; o; o >>= 1) { if (t < o) red[t] = fmaxf(red[t], red[t + o]); __syncthreads(); }
  m = red[0]; __syncthreads();

  float lsum = 0.f;
  for (int j = t; j < C; j += 256) { float e = expf(sm[j] - m); w[j] = e; lsum += e; }
  red[t] = lsum; __syncthreads();
  for (int o = 128; o; o >>= 1) { if (t < o) red[t] += red[t + o]; __syncthreads(); }
  float S = red[0]; __syncthreads();
  for (int j = t; j < C; j += 256) w[j] = w[j] / S;
  __syncthreads();

  int d = t;
  int s0 = lo + c * C;
  const float* kp = k + (s0 * BSZ + b) * DM + d;
  const float* vp = v + (s0 * BSZ + b) * DM + d;
  float ak = 0.f, av = 0.f;
  for (int j = 0; j < C; ++j) {
    float wj = w[j];
    ak += wj * kp[0];
    av += wj * vp[0];
    kp += BSZ * DM; vp += BSZ * DM;
  }
  kc[(b * SPAT + c) * DM + d] = ak;
  vc[(b * SPAT + c) * DM + d] = av;
}

// -------- K5/K7: tiled fp32 GEMM: C[r][n] = A[r][:] @ W + bias --------
// mode 0: A gathered from q layout (s,b,d); out linear [b*1600+s]
// mode 1: A linear, rows with (r%1600)>=n_cl invalid (skipped)
// mode 2: A linear; out remapped to (s*8+b)*256 (final output transpose)
__global__ __launch_bounds__(256) void gemm_kernel(
    const float* __restrict__ A, const float* __restrict__ W,
    const float* __restrict__ bias, float* __restrict__ Cout,
    int mode, const int* __restrict__ meta)
{
  __shared__ float As[16][68];
  __shared__ float Ws[16][68];
  int bm = blockIdx.x, bn = blockIdx.y;
  int row0 = bm * 64, col0 = bn * 64;
  int n_cl = SPAT;
  if (mode == 1) {
    n_cl = meta[3];
    int s0 = row0 % SPAT;            // 1600/64==25 -> block stays within one b
    if (s0 >= n_cl) return;
  }
  int tid = threadIdx.x;
  int mA = tid >> 2, kA = (tid & 3) * 4;
  int kW = tid >> 4, nW = (tid & 15) * 4;
  int r = row0 + mA;
  const float* Arow;
  if (mode == 0) { int b = r / SPAT, s = r - b * SPAT; Arow = A + (s * BSZ + b) * DM; }
  else           { Arow = A + r * DM; }
  const float* Wrow = W + kW * DM + col0 + nW;
  int ty = tid >> 4, tx = tid & 15;
  float acc[4][4] = {};

  for (int k0 = 0; k0 < DM; k0 += 16) {
    float4 a4 = *(const float4*)(Arow + k0 + kA);
    As[kA + 0][mA] = a4.x; As[kA + 1][mA] = a4.y;
    As[kA + 2][mA] = a4.z; As[kA + 3][mA] = a4.w;
    float4 w4 = *(const float4*)(Wrow + k0 * DM);
    *(float4*)&Ws[kW][nW] = w4;
    __syncthreads();
    #pragma unroll
    for (int kk = 0; kk < 16; ++kk) {
      float4 av = *(const float4*)&As[kk][ty * 4];
      float4 wv = *(const float4*)&Ws[kk][tx * 4];
      acc[0][0] += av.x * wv.x; acc[0][1] += av.x * wv.y; acc[0][2] += av.x * wv.z; acc[0][3] += av.x * wv.w;
      acc[1][0] += av.y * wv.x; acc[1][1] += av.y * wv.y; acc[1][2] += av.y * wv.z; acc[1][3] += av.y * wv.w;
      acc[2][0] += av.z * wv.x; acc[2][1] += av.z * wv.y; acc[2][2] += av.z * wv.z; acc[2][3] += av.z * wv.w;
      acc[3][0] += av.w * wv.x; acc[3][1] += av.w * wv.y; acc[3][2] += av.w * wv.z; acc[3][3] += av.w * wv.w;
    }
    __syncthreads();
  }

  float4 bi = *(const float4*)(bias + col0 + tx * 4);
  #pragma unroll
  for (int i = 0; i < 4; ++i) {
    int rr = row0 + ty * 4 + i;
    int bb = rr / SPAT, ss = rr - bb * SPAT;
    if (mode == 1 && ss >= n_cl) continue;
    float* outp;
    if (mode == 2) outp = Cout + (ss * BSZ + bb) * DM + col0 + tx * 4;
    else           outp = Cout + rr * DM + col0 + tx * 4;
    float4 o;
    o.x = acc[i][0] + bi.x; o.y = acc[i][1] + bi.y;
    o.z = acc[i][2] + bi.z; o.w = acc[i][3] + bi.w;
    *(float4*)outp = o;
  }
}

// -------- K6: attention v6 — LDS-staged K/V, 2-way cluster split --------
// Block: 256 thd = 128 q-rows x 2 cluster-stripes (waves 0-1: stripe 0,
// waves 2-3: stripe 1). K/V staged as 2x64-cluster chunks (coalesced f4,
// row stride 36 floats for bank spread; compute reads wave-uniform ->
// broadcast). Chunked online softmax (1 rescale / 8 clusters). Partials
// merged through LDS. NO min-waves hint (round-4 lesson: forcing 64 VGPR
// spilled ~1GB). Register K/V streaming is a proven dead end (rounds 4-5).
#define ACH 64
__global__ __launch_bounds__(256) void attn_kernel(
    const float* __restrict__ Qp, const float* __restrict__ Kp,
    const float* __restrict__ Vp, const int* __restrict__ meta,
    float* __restrict__ ctx)
{
  __shared__ float KV[4][ACH][36];   // [K0,K1,V0,V1][cluster][36]
  int b = blockIdx.y, h = blockIdx.z;
  int t = threadIdx.x;
  int sub = t >> 7;                  // cluster stripe (uniform per wave)
  int r = t & 127;
  int s = blockIdx.x * 128 + r;      // 13*128 = 1664 >= 1600
  bool act = s < SPAT;
  int n_cl = meta[3];

  const float* Kb = Kp + (size_t)(b * SPAT) * DM + h * DH;
  const float* Vb = Vp + (size_t)(b * SPAT) * DM + h * DH;

  float4 q[8];
  if (act) {
    const float* qrow = Qp + (size_t)(b * SPAT + s) * DM + h * DH;
    #pragma unroll
    for (int i = 0; i < 8; ++i) q[i] = *(const float4*)(qrow + i * 4);
  } else {
    #pragma unroll
    for (int i = 0; i < 8; ++i) q[i] = make_float4(0.f, 0.f, 0.f, 0.f);
  }

  float4 acc[8];
  #pragma unroll
  for (int i = 0; i < 8; ++i) acc[i] = make_float4(0.f, 0.f, 0.f, 0.f);
  float m = -1e30f, l = 0.f;         // finite init: no inf-inf NaN

  for (int base = 0; base < n_cl; base += 2 * ACH) {
    // cooperative stage: 4 arrays x 64 rows x 8 float4 (clamped rows are
    // finite garbage; their scores get -inf masked)
    for (int i = t; i < 4 * ACH * 8; i += 256) {
      int arr = i >> 9;
      int rem = i & 511;
      int row = rem >> 3, seg = rem & 7;
      int c = base + ((arr & 1) ? ACH : 0) + row;
      if (c > SPAT - 1) c = SPAT - 1;
      const float* src = ((arr < 2) ? Kb : Vb) + (size_t)c * DM + seg * 4;
      *(float4*)&KV[arr][row][seg * 4] = *(const float4*)src;
    }
    __syncthreads();

    int cst = base + sub * ACH;      // wave-uniform
    if (cst < n_cl) {
      const float (*Kc)[36] = KV[sub];
      const float (*Vc)[36] = KV[2 + sub];
      for (int j0 = 0; j0 < ACH; j0 += 8) {
        float sc[8];
        #pragma unroll
        for (int jj = 0; jj < 8; ++jj) {
          const float* kr = Kc[j0 + jj];
          float d0 = 0.f, d1 = 0.f, d2 = 0.f, d3 = 0.f;
          #pragma unroll
          for (int i = 0; i < 8; ++i) {
            float4 kv = *(const float4*)(kr + i * 4);
            d0 = fmaf(q[i].x, kv.x, d0);
            d1 = fmaf(q[i].y, kv.y, d1);
            d2 = fmaf(q[i].z, kv.z, d2);
            d3 = fmaf(q[i].w, kv.w, d3);
          }
          sc[jj] = (d0 + d1) + (d2 + d3);
        }
        #pragma unroll
        for (int jj = 0; jj < 8; ++jj)
          sc[jj] = (cst + j0 + jj < n_cl) ? sc[jj] : -INFINITY;

        float mc = sc[0];
        #pragma unroll
        for (int jj = 1; jj < 8; ++jj) mc = fmaxf(mc, sc[jj]);
        float nm = fmaxf(m, mc);
        float corr = __expf(m - nm);
        m = nm;
        l *= corr;
        #pragma unroll
        for (int i = 0; i < 8; ++i) {
          acc[i].x *= corr; acc[i].y *= corr; acc[i].z *= corr; acc[i].w *= corr;
        }
        #pragma unroll
        for (int jj = 0; jj < 8; ++jj) {
          float p = __expf(sc[jj] - m);
          l += p;
          const float* vr = Vc[j0 + jj];
          #pragma unroll
          for (int i = 0; i < 8; ++i) {
            float4 vv = *(const float4*)(vr + i * 4);
            acc[i].x = fmaf(p, vv.x, acc[i].x);
            acc[i].y = fmaf(p, vv.y, acc[i].y);
            acc[i].z = fmaf(p, vv.z, acc[i].z);
            acc[i].w = fmaf(p, vv.w, acc[i].w);
          }
        }
      }
    }
    __syncthreads();
  }

  // merge sub1 partials into sub0 via LDS (reuse KV as scratch)
  float* mrg = &KV[0][0][0];         // 128 rows x 34 floats = 17.4 KB
  if (sub == 1) {
    float* dst = mrg + r * 34;
    dst[0] = m; dst[1] = l;
    #pragma unroll
    for (int i = 0; i < 8; ++i) {
      dst[2 + i * 4 + 0] = acc[i].x; dst[2 + i * 4 + 1] = acc[i].y;
      dst[2 + i * 4 + 2] = acc[i].z; dst[2 + i * 4 + 3] = acc[i].w;
    }
  }
  __syncthreads();
  if (sub == 0 && act) {
    const float* src = mrg + r * 34;
    float m1 = src[0], l1 = src[1];
    float M = fmaxf(m, m1);
    float f0 = __expf(m - M), f1 = __expf(m1 - M);
    float L = l * f0 + l1 * f1;
    float inv = 1.f / (L * 32.f);
    float* orow = ctx + (size_t)(b * SPAT + s) * DM + h * DH;
    #pragma unroll
    for (int i = 0; i < 8; ++i) {
      float4 o;
      o.x = (acc[i].x * f0 + src[2 + i * 4 + 0] * f1) * inv;
      o.y = (acc[i].y * f0 + src[2 + i * 4 + 1] * f1) * inv;
      o.z = (acc[i].z * f0 + src[2 + i * 4 + 2] * f1) * inv;
      o.w = (acc[i].w * f0 + src[2 + i * 4 + 3] * f1) * inv;
      *(float4*)(orow + i * 4) = o;
    }
  }
}

extern "C" void kernel_launch(void* const* d_in, const int* in_sizes, int n_in,
                              void* d_out, int out_size, void* d_ws, size_t ws_size,
                              hipStream_t stream) {
  const float* q  = (const float*)d_in[0];
  const float* k  = (const float*)d_in[1];
  const float* v  = (const float*)d_in[2];
  const float* Wq = (const float*)d_in[5];
  const float* bq = (const float*)d_in[6];
  const float* Wk = (const float*)d_in[7];
  const float* bk = (const float*)d_in[8];
  const float* Wv = (const float*)d_in[9];
  const float* bv = (const float*)d_in[10];
  const float* Wo = (const float*)d_in[11];
  const float* bo = (const float*)d_in[12];
  const float* Wp = (const float*)d_in[13];
  const float* bp = (const float*)d_in[14];
  const float* gk = (const float*)d_in[15];
  const float* sb = (const float*)d_in[16];
  float* out = (float*)d_out;

  char* ws = (char*)d_ws;
  int*   meta   = (int*)ws;                                  // 256 B
  float* logits = (float*)(ws + 256);                        // 12800 f32
  float* smooth = logits + BSZ * SPAT;                       // 12800 f32
  float* bufA   = (float*)(ws + 256 + 2 * BSZ * SPAT * 4);   // 13.1 MB: kc, then Vp
  float* bufB   = bufA + BSZ * SPAT * DM;                    // vc, then ctx
  float* bufC   = bufB + BSZ * SPAT * DM;                    // Qp
  float* bufD   = bufC + BSZ * SPAT * DM;                    // Kp

  logits_kernel<<<BSZ * SPAT / 4, 256, 0, stream>>>(k, Wp, bp, logits);
  entropy_kernel<<<BSZ, 256, 0, stream>>>(logits, gk, smooth);
  clsize_kernel<<<1, 256, 0, stream>>>(smooth, sb, meta);
  cluster_kernel<<<dim3(SPAT, BSZ), 256, 0, stream>>>(k, v, smooth, meta, bufA, bufB);
  gemm_kernel<<<dim3(200, 4), 256, 0, stream>>>(q,    Wq, bq, bufC, 0, meta);  // Qp
  gemm_kernel<<<dim3(200, 4), 256, 0, stream>>>(bufA, Wk, bk, bufD, 1, meta);  // Kp
  gemm_kernel<<<dim3(200, 4), 256, 0, stream>>>(bufB, Wv, bv, bufA, 1, meta);  // Vp (reuse kc)
  attn_kernel<<<dim3(13, BSZ, NH), 256, 0, stream>>>(bufC, bufD, bufA, meta, bufB); // ctx (reuse vc)
  gemm_kernel<<<dim3(200, 4), 256, 0, stream>>>(bufB, Wo, bo, out, 2, meta);   // final + transpose
}

// Round 7
// 223.030 us; speedup vs baseline: 5.4089x; 1.2721x over previous
//
#include <hip/hip_runtime.h>
#include <math.h>

#define SPAT 1600
#define BSZ 8
#define DM 256
#define NH 8
#define DH 32

typedef __attribute__((ext_vector_type(8))) short bf16x8;
typedef __attribute__((ext_vector_type(4))) float f32x4;

static __device__ __forceinline__ unsigned short f2bf(float x) {
  unsigned u = __float_as_uint(x);
  unsigned r = (u + 0x7fff + ((u >> 16) & 1)) >> 16;
  return (unsigned short)r;
}
static __device__ __forceinline__ float bf2f(unsigned short h) {
  return __uint_as_float(((unsigned)h) << 16);
}

// ---------------- K1: logits[b][s] = k[s][b][:] . Wp + bp ----------------
__global__ __launch_bounds__(256) void logits_kernel(
    const float* __restrict__ k, const float* __restrict__ Wp,
    const float* __restrict__ bp, float* __restrict__ logits)
{
  int wave = threadIdx.x >> 6, lane = threadIdx.x & 63;
  int idx = blockIdx.x * 4 + wave;           // 0..12799
  if (idx >= BSZ * SPAT) return;
  int b = idx / SPAT, s = idx - b * SPAT;
  const float4 kv = *(const float4*)(k + (s * BSZ + b) * DM + lane * 4);
  const float4 wv = *(const float4*)(Wp + lane * 4);
  float sum = kv.x * wv.x + kv.y * wv.y + kv.z * wv.z + kv.w * wv.w;
  #pragma unroll
  for (int off = 32; off; off >>= 1) sum += __shfl_xor(sum, off);
  if (lane == 0) logits[idx] = sum + bp[0];
}

// -------- K2: per-batch softmax -> entropy -> gaussian conv (same) --------
__global__ __launch_bounds__(256) void entropy_kernel(
    const float* __restrict__ logits, const float* __restrict__ gk,
    float* __restrict__ smooth)
{
  int b = blockIdx.x;
  int t = threadIdx.x;
  const float* L = logits + b * SPAT;
  __shared__ float entpad[SPAT + 28];
  __shared__ float red[256];

  for (int i = t; i < SPAT + 28; i += 256) entpad[i] = 0.f;

  float m = -INFINITY;
  for (int i = t; i < SPAT; i += 256) m = fmaxf(m, L[i]);
  red[t] = m; __syncthreads();
  for (int o = 128; o; o >>= 1) { if (t < o) red[t] = fmaxf(red[t], red[t + o]); __syncthreads(); }
  m = red[0]; __syncthreads();

  float lsum = 0.f;
  for (int i = t; i < SPAT; i += 256) {
    float e = expf(L[i] - m);
    entpad[14 + i] = e;
    lsum += e;
  }
  red[t] = lsum; __syncthreads();
  for (int o = 128; o; o >>= 1) { if (t < o) red[t] += red[t + o]; __syncthreads(); }
  float S = red[0]; __syncthreads();

  for (int i = t; i < SPAT; i += 256) {
    float p = entpad[14 + i] / S + 1e-8f;
    entpad[14 + i] = -p * logf(p) / 0.6931471805599453f;
  }
  __syncthreads();

  for (int i = t; i < SPAT; i += 256) {
    float acc = 0.f;
    #pragma unroll
    for (int u = 0; u < 29; ++u) acc += entpad[i + u] * gk[28 - u];
    smooth[b * SPAT + i] = acc;
  }
}

// -------- K3: sobel sign transitions -> cluster size -> meta --------
// meta: [0]=C, [1]=lo, [2]=rem, [3]=n_cl
__global__ __launch_bounds__(256) void clsize_kernel(
    const float* __restrict__ smooth, const float* __restrict__ sobel,
    int* __restrict__ meta)
{
  __shared__ int cnt;
  __shared__ float msum;
  int t = threadIdx.x;
  float sb0 = sobel[0], sb1 = sobel[1], sb2 = sobel[2];
  if (t == 0) msum = 0.f;
  for (int b = 0; b < BSZ; ++b) {
    const float* sm = smooth + b * SPAT;
    if (t == 0) cnt = 0;
    __syncthreads();
    int local = 0;
    for (int i = 1 + t; i < SPAT; i += 256) {
      float smL = (i - 2 >= 0) ? sm[i - 2] : 0.f;
      float a = sm[i - 1];
      float c = sm[i];
      float smR = (i + 1 < SPAT) ? sm[i + 1] : 0.f;
      float stepPrev = smL * sb2 + a * sb1 + c * sb0;   // step[i-1]
      float stepCur  = a * sb2 + c * sb1 + smR * sb0;   // step[i]
      int sPrev = stepPrev > 0.f;
      int sCur  = stepCur  > 0.f;
      local += (sPrev != sCur);
    }
    atomicAdd(&cnt, local);
    __syncthreads();
    if (t == 0) msum += 1600.f / (float)(cnt + 1);
    __syncthreads();
  }
  if (t == 0) {
    float mean = msum / 8.f;
    int C = (int)rintf(mean);
    if (C < 1) C = 1;
    int rem = SPAT % C;
    int lo = rem / 2;
    int n_cl = (SPAT - rem) / C;
    meta[0] = C; meta[1] = lo; meta[2] = rem; meta[3] = n_cl;
  }
}

// -------- K4: entropy-softmax weighted cluster pooling of k, v --------
__global__ __launch_bounds__(256) void cluster_kernel(
    const float* __restrict__ k, const float* __restrict__ v,
    const float* __restrict__ smooth, const int* __restrict__ meta,
    float* __restrict__ kc, float* __restrict__ vc)
{
  int c = blockIdx.x, b = blockIdx.y;
  int C = meta[0], lo = meta[1], n_cl = meta[3];
  if (c >= n_cl) return;
  __shared__ float w[SPAT];
  __shared__ float red[256];
  int t = threadIdx.x;
  const float* sm = smooth + b * SPAT + lo + c * C;

  float m = -INFINITY;
  for (int j = t; j < C; j += 256) m = fmaxf(m, sm[j]);
  red[t] = m; __syncthreads();
  for (int o = 128; o; o >>= 1) { if (t < o) red[t] = fmaxf(red[t], red[t + o]); __syncthreads(); }
  m = red[0]; __syncthreads();

  float lsum = 0.f;
  for (int j = t; j < C; j += 256) { float e = expf(sm[j] - m); w[j] = e; lsum += e; }
  red[t] = lsum; __syncthreads();
  for (int o = 128; o; o >>= 1) { if (t < o) red[t] += red[t + o]; __syncthreads(); }
  float S = red[0]; __syncthreads();
  for (int j = t; j < C; j += 256) w[j] = w[j] / S;
  __syncthreads();

  int d = t;
  int s0 = lo + c * C;
  const float* kp = k + (s0 * BSZ + b) * DM + d;
  const float* vp = v + (s0 * BSZ + b) * DM + d;
  float ak = 0.f, av = 0.f;
  for (int j = 0; j < C; ++j) {
    float wj = w[j];
    ak += wj * kp[0];
    av += wj * vp[0];
    kp += BSZ * DM; vp += BSZ * DM;
  }
  kc[(b * SPAT + c) * DM + d] = ak;
  vc[(b * SPAT + c) * DM + d] = av;
}

// -------- K5/K7: tiled fp32 GEMM: C[r][n] = A[r][:] @ W + bias --------
__global__ __launch_bounds__(256) void gemm_kernel(
    const float* __restrict__ A, const float* __restrict__ W,
    const float* __restrict__ bias, float* __restrict__ Cout,
    int mode, const int* __restrict__ meta)
{
  __shared__ float As[16][68];
  __shared__ float Ws[16][68];
  int bm = blockIdx.x, bn = blockIdx.y;
  int row0 = bm * 64, col0 = bn * 64;
  int n_cl = SPAT;
  if (mode == 1) {
    n_cl = meta[3];
    int s0 = row0 % SPAT;            // 1600/64==25 -> block stays within one b
    if (s0 >= n_cl) return;
  }
  int tid = threadIdx.x;
  int mA = tid >> 2, kA = (tid & 3) * 4;
  int kW = tid >> 4, nW = (tid & 15) * 4;
  int r = row0 + mA;
  const float* Arow;
  if (mode == 0) { int b = r / SPAT, s = r - b * SPAT; Arow = A + (s * BSZ + b) * DM; }
  else           { Arow = A + r * DM; }
  const float* Wrow = W + kW * DM + col0 + nW;
  int ty = tid >> 4, tx = tid & 15;
  float acc[4][4] = {};

  for (int k0 = 0; k0 < DM; k0 += 16) {
    float4 a4 = *(const float4*)(Arow + k0 + kA);
    As[kA + 0][mA] = a4.x; As[kA + 1][mA] = a4.y;
    As[kA + 2][mA] = a4.z; As[kA + 3][mA] = a4.w;
    float4 w4 = *(const float4*)(Wrow + k0 * DM);
    *(float4*)&Ws[kW][nW] = w4;
    __syncthreads();
    #pragma unroll
    for (int kk = 0; kk < 16; ++kk) {
      float4 av = *(const float4*)&As[kk][ty * 4];
      float4 wv = *(const float4*)&Ws[kk][tx * 4];
      acc[0][0] += av.x * wv.x; acc[0][1] += av.x * wv.y; acc[0][2] += av.x * wv.z; acc[0][3] += av.x * wv.w;
      acc[1][0] += av.y * wv.x; acc[1][1] += av.y * wv.y; acc[1][2] += av.y * wv.z; acc[1][3] += av.y * wv.w;
      acc[2][0] += av.z * wv.x; acc[2][1] += av.z * wv.y; acc[2][2] += av.z * wv.z; acc[2][3] += av.z * wv.w;
      acc[3][0] += av.w * wv.x; acc[3][1] += av.w * wv.y; acc[3][2] += av.w * wv.z; acc[3][3] += av.w * wv.w;
    }
    __syncthreads();
  }

  float4 bi = *(const float4*)(bias + col0 + tx * 4);
  #pragma unroll
  for (int i = 0; i < 4; ++i) {
    int rr = row0 + ty * 4 + i;
    int bb = rr / SPAT, ss = rr - bb * SPAT;
    if (mode == 1 && ss >= n_cl) continue;
    float* outp;
    if (mode == 2) outp = Cout + (ss * BSZ + bb) * DM + col0 + tx * 4;
    else           outp = Cout + rr * DM + col0 + tx * 4;
    float4 o;
    o.x = acc[i][0] + bi.x; o.y = acc[i][1] + bi.y;
    o.z = acc[i][2] + bi.z; o.w = acc[i][3] + bi.w;
    *(float4*)outp = o;
  }
}

// -------- P1: split Qp,Kp fp32 -> bf16 hi/lo, layout [bh][s][32] --------
__global__ __launch_bounds__(256) void splitqk_kernel(
    const float* __restrict__ Qp, const float* __restrict__ Kp,
    unsigned short* __restrict__ Qh, unsigned short* __restrict__ Ql,
    unsigned short* __restrict__ Kh, unsigned short* __restrict__ Kl)
{
  int tg = blockIdx.x * 256 + threadIdx.x;   // 409600
  int row = tg >> 5;                         // 0..12799 = b*1600+s
  int d0 = (tg & 31) * 8;
  int b = row / SPAT, s = row - b * SPAT;
  int h = d0 >> 5, dl = d0 & 31;
  size_t ioff = (size_t)row * DM + d0;
  size_t ooff = ((size_t)(b * NH + h) * SPAT + s) * DH + dl;

  {
    float4 a = *(const float4*)(Qp + ioff);
    float4 c = *(const float4*)(Qp + ioff + 4);
    float x[8] = {a.x, a.y, a.z, a.w, c.x, c.y, c.z, c.w};
    bf16x8 hv, lv;
    #pragma unroll
    for (int j = 0; j < 8; ++j) {
      unsigned short hb = f2bf(x[j]);
      hv[j] = (short)hb;
      lv[j] = (short)f2bf(x[j] - bf2f(hb));
    }
    *(bf16x8*)(Qh + ooff) = hv;
    *(bf16x8*)(Ql + ooff) = lv;
  }
  {
    float4 a = *(const float4*)(Kp + ioff);
    float4 c = *(const float4*)(Kp + ioff + 4);
    float x[8] = {a.x, a.y, a.z, a.w, c.x, c.y, c.z, c.w};
    bf16x8 hv, lv;
    #pragma unroll
    for (int j = 0; j < 8; ++j) {
      unsigned short hb = f2bf(x[j]);
      hv[j] = (short)hb;
      lv[j] = (short)f2bf(x[j] - bf2f(hb));
    }
    *(bf16x8*)(Kh + ooff) = hv;
    *(bf16x8*)(Kl + ooff) = lv;
  }
}

// -------- P2: Vp fp32 [b*1600+c][256] -> V^T bf16 hi/lo [bh][d][1600] --------
__global__ __launch_bounds__(256) void transposev_kernel(
    const float* __restrict__ Vp,
    unsigned short* __restrict__ Vth, unsigned short* __restrict__ Vtl)
{
  __shared__ float tile[64][33];
  int c0 = blockIdx.x * 64;                 // 25
  int bh = blockIdx.y;                      // 64
  int b = bh >> 3, h = bh & 7;
  int t = threadIdx.x;

  int row = t >> 2, dseg = (t & 3) * 8;     // 64 rows x 32 d
  const float* src = Vp + ((size_t)(b * SPAT + c0 + row)) * DM + h * DH + dseg;
  float4 a = *(const float4*)src;
  float4 c4 = *(const float4*)(src + 4);
  tile[row][dseg + 0] = a.x;  tile[row][dseg + 1] = a.y;
  tile[row][dseg + 2] = a.z;  tile[row][dseg + 3] = a.w;
  tile[row][dseg + 4] = c4.x; tile[row][dseg + 5] = c4.y;
  tile[row][dseg + 6] = c4.z; tile[row][dseg + 7] = c4.w;
  __syncthreads();

  int d = t >> 3, cs = (t & 7) * 8;         // 32 d x 64 c
  bf16x8 hv, lv;
  #pragma unroll
  for (int j = 0; j < 8; ++j) {
    float x = tile[cs + j][d];
    unsigned short hb = f2bf(x);
    hv[j] = (short)hb;
    lv[j] = (short)f2bf(x - bf2f(hb));
  }
  size_t off = ((size_t)bh * DH + d) * SPAT + c0 + cs;
  *(bf16x8*)(Vth + off) = hv;
  *(bf16x8*)(Vtl + off) = lv;
}

// -------- K6: MFMA attention (bf16x3 split-fp32), 16 q-rows per wave --------
// Swapped QK^T: S^T[c][s] = mfma(A=K, B=Q). C layout: col=lane&15=s,
// row=(lane>>4)*4+reg=c-local (m89-verified). PV: O^T[d][s] =
// mfma(A=V^T, B=P) accumulating 2 d-tiles x f32x4. No LDS, no barriers.
__global__ __launch_bounds__(256) void attn_mfma_kernel(
    const unsigned short* __restrict__ Qh, const unsigned short* __restrict__ Ql,
    const unsigned short* __restrict__ Kh, const unsigned short* __restrict__ Kl,
    const unsigned short* __restrict__ Vth, const unsigned short* __restrict__ Vtl,
    const int* __restrict__ meta, float* __restrict__ ctx)
{
  int b = blockIdx.y, h = blockIdx.z, bh = b * NH + h;
  int t = threadIdx.x;
  int w = t >> 6, l = t & 63;
  int g = l >> 4, sig = l & 15;
  int n_cl = meta[3];
  int s = blockIdx.x * 64 + w * 16 + sig;   // 25*64 = 1600

  size_t qoff = ((size_t)bh * SPAT + s) * DH + g * 8;
  bf16x8 qh = *(const bf16x8*)(Qh + qoff);
  bf16x8 ql = *(const bf16x8*)(Ql + qoff);

  const unsigned short* Kbh = Kh + (size_t)bh * SPAT * DH;
  const unsigned short* Kbl = Kl + (size_t)bh * SPAT * DH;
  const unsigned short* Vbh = Vth + (size_t)bh * DH * SPAT;
  const unsigned short* Vbl = Vtl + (size_t)bh * DH * SPAT;

  f32x4 o0 = {0.f, 0.f, 0.f, 0.f}, o1 = {0.f, 0.f, 0.f, 0.f};
  float m = -1e30f, lsum = 0.f;

  for (int c0 = 0; c0 < n_cl; c0 += 64) {
    // ---- QK^T: 4 cluster-tiles of 16, bf16x3 ----
    f32x4 sc[4];
    #pragma unroll
    for (int ct = 0; ct < 4; ++ct) {
      int cr = c0 + ct * 16 + sig;
      if (cr > SPAT - 1) cr = SPAT - 1;     // clamped rows get -inf masked
      size_t ko = (size_t)cr * DH + g * 8;
      bf16x8 kh = *(const bf16x8*)(Kbh + ko);
      bf16x8 kl = *(const bf16x8*)(Kbl + ko);
      f32x4 a = {0.f, 0.f, 0.f, 0.f};
      a = __builtin_amdgcn_mfma_f32_16x16x32_bf16(kh, qh, a, 0, 0, 0);
      a = __builtin_amdgcn_mfma_f32_16x16x32_bf16(kh, ql, a, 0, 0, 0);
      a = __builtin_amdgcn_mfma_f32_16x16x32_bf16(kl, qh, a, 0, 0, 0);
      sc[ct] = a;
    }
    // ---- mask tail clusters ----
    #pragma unroll
    for (int ct = 0; ct < 4; ++ct) {
      #pragma unroll
      for (int r = 0; r < 4; ++r) {
        int c = c0 + ct * 16 + g * 4 + r;
        if (c >= n_cl) sc[ct][r] = -INFINITY;
      }
    }
    // ---- chunk max per s (in-lane 16 + cross-lane over groups) ----
    float mc = sc[0][0];
    #pragma unroll
    for (int ct = 0; ct < 4; ++ct) {
      #pragma unroll
      for (int r = 0; r < 4; ++r) mc = fmaxf(mc, sc[ct][r]);
    }
    mc = fmaxf(mc, __shfl_xor(mc, 16));
    mc = fmaxf(mc, __shfl_xor(mc, 32));
    float nm = fmaxf(m, mc);
    float corr = __expf(m - nm);
    m = nm;
    lsum *= corr; o0 *= corr; o1 *= corr;
    // ---- p = exp(sc - m), accumulate partial denom ----
    #pragma unroll
    for (int ct = 0; ct < 4; ++ct) {
      #pragma unroll
      for (int r = 0; r < 4; ++r) {
        float p = __expf(sc[ct][r] - m);
        sc[ct][r] = p;
        lsum += p;
      }
    }
    // ---- PV: per 32-cluster pair, regroup P to B-operand, bf16x3 ----
    #pragma unroll
    for (int pr = 0; pr < 2; ++pr) {
      if (c0 + pr * 32 >= n_cl) continue;   // wave-uniform skip
      float v[8];
      #pragma unroll
      for (int e = 0; e < 8; ++e) {
        // target: B elem e of lane(g,sig) = P[c0+32pr+8g+e][s=sig]
        // source: tile 2pr+(g>>1), reg e&3, lane 16*(2*(g&1)+(e>>2))+sig
        int src = ((g & 1) << 5) + ((e >> 2) << 4) + sig;
        float va = __shfl(sc[2 * pr + 0][e & 3], src);
        float vb = __shfl(sc[2 * pr + 1][e & 3], src);
        v[e] = (g >= 2) ? vb : va;
      }
      bf16x8 pbh, pbl;
      #pragma unroll
      for (int e = 0; e < 8; ++e) {
        unsigned short hb = f2bf(v[e]);
        pbh[e] = (short)hb;
        pbl[e] = (short)f2bf(v[e] - bf2f(hb));
      }
      int cb = c0 + pr * 32 + g * 8;
      if (cb > SPAT - 8) cb = SPAT - 8;     // clamped cols multiply p=0
      {
        size_t vo = (size_t)(0 * 16 + sig) * SPAT + cb;
        bf16x8 vh = *(const bf16x8*)(Vbh + vo);
        bf16x8 vl = *(const bf16x8*)(Vbl + vo);
        o0 = __builtin_amdgcn_mfma_f32_16x16x32_bf16(vh, pbh, o0, 0, 0, 0);
        o0 = __builtin_amdgcn_mfma_f32_16x16x32_bf16(vh, pbl, o0, 0, 0, 0);
        o0 = __builtin_amdgcn_mfma_f32_16x16x32_bf16(vl, pbh, o0, 0, 0, 0);
      }
      {
        size_t vo = (size_t)(16 + sig) * SPAT + cb;
        bf16x8 vh = *(const bf16x8*)(Vbh + vo);
        bf16x8 vl = *(const bf16x8*)(Vbl + vo);
        o1 = __builtin_amdgcn_mfma_f32_16x16x32_bf16(vh, pbh, o1, 0, 0, 0);
        o1 = __builtin_amdgcn_mfma_f32_16x16x32_bf16(vh, pbl, o1, 0, 0, 0);
        o1 = __builtin_amdgcn_mfma_f32_16x16x32_bf16(vl, pbh, o1, 0, 0, 0);
      }
    }
  }

  // ---- finalize: full denom across groups, write O^T frags ----
  lsum += __shfl_xor(lsum, 16);
  lsum += __shfl_xor(lsum, 32);
  float inv = 1.f / (lsum * 32.f);
  float* orow = ctx + ((size_t)(b * SPAT + s)) * DM + h * DH;
  float4 w0, w1;
  w0.x = o0[0] * inv; w0.y = o0[1] * inv; w0.z = o0[2] * inv; w0.w = o0[3] * inv;
  w1.x = o1[0] * inv; w1.y = o1[1] * inv; w1.z = o1[2] * inv; w1.w = o1[3] * inv;
  *(float4*)(orow + g * 4) = w0;           // d = 4g+r
  *(float4*)(orow + 16 + g * 4) = w1;      // d = 16+4g+r
}

extern "C" void kernel_launch(void* const* d_in, const int* in_sizes, int n_in,
                              void* d_out, int out_size, void* d_ws, size_t ws_size,
                              hipStream_t stream) {
  const float* q  = (const float*)d_in[0];
  const float* k  = (const float*)d_in[1];
  const float* v  = (const float*)d_in[2];
  const float* Wq = (const float*)d_in[5];
  const float* bq = (const float*)d_in[6];
  const float* Wk = (const float*)d_in[7];
  const float* bk = (const float*)d_in[8];
  const float* Wv = (const float*)d_in[9];
  const float* bv = (const float*)d_in[10];
  const float* Wo = (const float*)d_in[11];
  const float* bo = (const float*)d_in[12];
  const float* Wp = (const float*)d_in[13];
  const float* bp = (const float*)d_in[14];
  const float* gk = (const float*)d_in[15];
  const float* sb = (const float*)d_in[16];
  float* out = (float*)d_out;

  const size_t NE = (size_t)BSZ * SPAT * DM;                 // 3276800
  char* ws = (char*)d_ws;
  int*   meta   = (int*)ws;                                  // 256 B
  float* logits = (float*)(ws + 256);                        // 12800 f32
  float* smooth = logits + BSZ * SPAT;                       // 12800 f32
  float* bufA   = (float*)(ws + 256 + 2 * BSZ * SPAT * 4);   // kc -> Vp -> ctx
  float* bufB   = bufA + NE;                                 // vc -> Vth|Vtl
  float* bufC   = bufB + NE;                                 // Qp
  float* bufD   = bufC + NE;                                 // Kp
  unsigned short* Qh = (unsigned short*)(bufD + NE);         // 4 x 6.55 MB
  unsigned short* Ql = Qh + NE;
  unsigned short* Kh = Ql + NE;
  unsigned short* Kl = Kh + NE;
  unsigned short* Vth = (unsigned short*)bufB;               // aliases vc (dead)
  unsigned short* Vtl = Vth + NE;
  float* ctx = bufA;                                         // aliases Vp (dead)

  logits_kernel<<<BSZ * SPAT / 4, 256, 0, stream>>>(k, Wp, bp, logits);
  entropy_kernel<<<BSZ, 256, 0, stream>>>(logits, gk, smooth);
  clsize_kernel<<<1, 256, 0, stream>>>(smooth, sb, meta);
  cluster_kernel<<<dim3(SPAT, BSZ), 256, 0, stream>>>(k, v, smooth, meta, bufA, bufB);
  gemm_kernel<<<dim3(200, 4), 256, 0, stream>>>(q,    Wq, bq, bufC, 0, meta);  // Qp
  gemm_kernel<<<dim3(200, 4), 256, 0, stream>>>(bufA, Wk, bk, bufD, 1, meta);  // Kp
  gemm_kernel<<<dim3(200, 4), 256, 0, stream>>>(bufB, Wv, bv, bufA, 1, meta);  // Vp
  splitqk_kernel<<<1600, 256, 0, stream>>>(bufC, bufD, Qh, Ql, Kh, Kl);
  transposev_kernel<<<dim3(25, 64), 256, 0, stream>>>(bufA, Vth, Vtl);
  attn_mfma_kernel<<<dim3(25, BSZ, NH), 256, 0, stream>>>(Qh, Ql, Kh, Kl, Vth, Vtl, meta, ctx);
  gemm_kernel<<<dim3(200, 4), 256, 0, stream>>>(ctx, Wo, bo, out, 2, meta);    // final + transpose
}